// Round 1
// baseline (930.628 us; speedup 1.0000x reference)
//
#include <hip/hip_runtime.h>

// SynesthesiaCentralOrchestrator: per-point Karcher mean of 4 unit quaternions,
// 10 fixed iterations (global convergence flag provably never fires in fp32).
// Quaternion stored as float4: .x=w, .y=x, .z=y, .w=z.

#define NPTS (2048 * 2048)

__device__ __forceinline__ float4 hprod(const float4 a, const float4 b) {
    // Hamilton product a ⊗ b
    return make_float4(
        a.x * b.x - a.y * b.y - a.z * b.z - a.w * b.w,
        a.x * b.y + a.y * b.x + a.z * b.w - a.w * b.z,
        a.x * b.z - a.y * b.w + a.z * b.x + a.w * b.y,
        a.x * b.w + a.y * b.z - a.z * b.y + a.w * b.x);
}

__device__ __forceinline__ float4 qnorm(const float4 q) {
    float n = sqrtf(q.x * q.x + q.y * q.y + q.z * q.z + q.w * q.w) + 1e-12f;
    float inv = 1.0f / n;
    return make_float4(q.x * inv, q.y * inv, q.z * inv, q.w * inv);
}

__global__ __launch_bounds__(256) void karcher_kernel(
    const float4* __restrict__ aud, const float4* __restrict__ vis,
    const float4* __restrict__ txt, const float4* __restrict__ gen,
    float* __restrict__ out, float* __restrict__ acc)
{
    const int i = blockIdx.x * 256 + threadIdx.x;

    float4 p[4];
    p[0] = qnorm(aud[i]);
    p[1] = qnorm(vis[i]);
    p[2] = qnorm(txt[i]);
    p[3] = qnorm(gen[i]);

    float4 mu = p[0];

    #pragma unroll 1
    for (int it = 0; it < 10; ++it) {
        // mu^{-1} = conjugate (mu is unit; ref multiplies by [1,-1,-1,-1])
        const float4 mi = make_float4(mu.x, -mu.y, -mu.z, -mu.w);

        float vx = 0.0f, vy = 0.0f, vz = 0.0f;
        #pragma unroll
        for (int k = 0; k < 4; ++k) {
            const float4 q = hprod(mi, p[k]);
            // quaternion_log: theta/sin(theta) * v, with w clipped.
            // sin(acos(w)) == sqrt(1-w^2) (identical math, cheaper).
            float w = fminf(fmaxf(q.x, -1.0f + 1e-7f), 1.0f - 1e-7f);
            float theta = acosf(w);
            float st = sqrtf(fmaxf(1.0f - w * w, 0.0f)) + 1e-9f;
            float s = theta / st;
            vx += s * q.y; vy += s * q.z; vz += s * q.w;
        }
        // weights = 1/4
        vx *= 0.25f; vy *= 0.25f; vz *= 0.25f;

        // quaternion_exp(mean_v)
        float th = sqrtf(vx * vx + vy * vy + vz * vz);
        float invt = 1.0f / (th + 1e-9f);
        float sth = __sinf(th);
        float cth = __cosf(th);
        float sc = sth * invt;
        float4 dm = make_float4(cth, sc * vx, sc * vy, sc * vz);

        mu = qnorm(hprod(mu, dm));
    }

    // Output 0: barycenter (B, L, 4)
    reinterpret_cast<float4*>(out)[i] = mu;

    // Output 1: eta = angle(det_s)/pi.  det_s imag parts are (a*b - a*b) == 0
    // exactly in fp32; real part = |q|^2 > 0  =>  angle == 0 exactly.
    out[4 * NPTS + i] = 0.0f;

    // Output 2 contribution: curvature^2 partial = |mu - mu/(|mu|+1e-12)|^2
    float n = sqrtf(mu.x * mu.x + mu.y * mu.y + mu.z * mu.z + mu.w * mu.w) + 1e-12f;
    float invn = 1.0f / n;
    float dx = mu.x - mu.x * invn;
    float dy = mu.y - mu.y * invn;
    float dz = mu.z - mu.z * invn;
    float dw = mu.w - mu.w * invn;
    float ss = dx * dx + dy * dy + dz * dz + dw * dw;

    // wave(64)-level reduction, one atomic per wave
    #pragma unroll
    for (int off = 32; off > 0; off >>= 1)
        ss += __shfl_down(ss, off, 64);
    if ((threadIdx.x & 63) == 0)
        atomicAdd(acc, ss);
}

__global__ void finish_kernel(const float* __restrict__ acc, float* __restrict__ out)
{
    out[5 * NPTS] = 1.0f / (1.0f + sqrtf(*acc));
}

extern "C" void kernel_launch(void* const* d_in, const int* in_sizes, int n_in,
                              void* d_out, int out_size, void* d_ws, size_t ws_size,
                              hipStream_t stream) {
    const float4* aud = (const float4*)d_in[0];
    const float4* vis = (const float4*)d_in[1];
    const float4* txt = (const float4*)d_in[2];
    const float4* gen = (const float4*)d_in[3];
    float* out = (float*)d_out;
    float* acc = (float*)d_ws;

    // d_ws is poisoned once and never re-poisoned: zero our accumulator each call.
    hipMemsetAsync(acc, 0, sizeof(float), stream);

    karcher_kernel<<<NPTS / 256, 256, 0, stream>>>(aud, vis, txt, gen, out, acc);
    finish_kernel<<<1, 1, 0, stream>>>(acc, out);
}

// Round 2
// 857.006 us; speedup vs baseline: 1.0859x; 1.0859x over previous
//
#include <hip/hip_runtime.h>

// SynesthesiaCentralOrchestrator: per-point Karcher mean of 4 unit quaternions,
// 10 fixed iterations (global convergence flag provably never fires in fp32).
// Quaternion stored as float4: .x=w, .y=x, .z=y, .w=z.
//
// R2: replace acosf + IEEE divisions with fused  s(w) = acos(w)/sqrt(1-w^2)
//     via 4-term polynomial + v_rsq;  all norms via v_rsq/v_rcp/v_sqrt
//     builtins (precise libm paths were ~5x the static instruction estimate).

#define NPTS (2048 * 2048)
#define PI_F 3.14159265358979f

__device__ __forceinline__ float frcp(float x) { return __builtin_amdgcn_rcpf(x); }
__device__ __forceinline__ float frsq(float x) { return __builtin_amdgcn_rsqf(x); }
__device__ __forceinline__ float fsqrt(float x) { return __builtin_amdgcn_sqrtf(x); }

__device__ __forceinline__ float4 hprod(const float4 a, const float4 b) {
    // Hamilton product a (x) b
    return make_float4(
        fmaf(a.x, b.x, -fmaf(a.y, b.y, fmaf(a.z, b.z, a.w * b.w))),
        fmaf(a.x, b.y, fmaf(a.y, b.x, fmaf(a.z, b.w, -a.w * b.z))),
        fmaf(a.x, b.z, fmaf(-a.y, b.w, fmaf(a.z, b.x, a.w * b.y))),
        fmaf(a.x, b.w, fmaf(a.y, b.z, fmaf(-a.z, b.y, a.w * b.x))));
}

__device__ __forceinline__ float4 qnorm_fast(const float4 q) {
    float inv = frsq(fmaf(q.x, q.x, fmaf(q.y, q.y, fmaf(q.z, q.z, q.w * q.w))));
    return make_float4(q.x * inv, q.y * inv, q.z * inv, q.w * inv);
}

// Accumulate  s(w) * vec(q)  where q = mi (x) pk,  s(w) = acos(w)/sqrt(1-w^2).
// acos(a) ~= sqrt(1-a) * t(a)  for a in [0,1], |err| <= 6.8e-5 rad.
__device__ __forceinline__ void log_accum(const float4 mi, const float4 pk,
                                          float& vx, float& vy, float& vz) {
    const float4 q = hprod(mi, pk);
    float w = fminf(fmaxf(q.x, -1.0f + 1e-7f), 1.0f - 1e-7f);
    float a = fabsf(w);
    float t = fmaf(a, fmaf(a, fmaf(a, -0.0187293f, 0.0742610f), -0.2121144f), 1.5707288f);
    float r1 = frsq(1.0f + a);
    float r2 = frsq(1.0f - a);          // clamp guarantees 1-a >= 1e-7
    float s = (w >= 0.0f) ? (t * r1) : (r1 * fmaf(PI_F, r2, -t));
    vx = fmaf(s, q.y, vx);
    vy = fmaf(s, q.z, vy);
    vz = fmaf(s, q.w, vz);
}

__global__ __launch_bounds__(256) void karcher_kernel(
    const float4* __restrict__ aud, const float4* __restrict__ vis,
    const float4* __restrict__ txt, const float4* __restrict__ gen,
    float* __restrict__ out, float* __restrict__ acc)
{
    const int i = blockIdx.x * 256 + threadIdx.x;

    float4 p0 = qnorm_fast(aud[i]);
    float4 p1 = qnorm_fast(vis[i]);
    float4 p2 = qnorm_fast(txt[i]);
    float4 p3 = qnorm_fast(gen[i]);

    float4 mu = p0;

    #pragma unroll 1
    for (int it = 0; it < 10; ++it) {
        const float4 mi = make_float4(mu.x, -mu.y, -mu.z, -mu.w);  // mu^-1 (unit)

        float vx = 0.0f, vy = 0.0f, vz = 0.0f;
        log_accum(mi, p0, vx, vy, vz);
        log_accum(mi, p1, vx, vy, vz);
        log_accum(mi, p2, vx, vy, vz);
        log_accum(mi, p3, vx, vy, vz);
        vx *= 0.25f; vy *= 0.25f; vz *= 0.25f;   // weights = 1/4

        // quaternion_exp(mean_v)
        float th = fsqrt(fmaf(vx, vx, fmaf(vy, vy, vz * vz)));
        float sc = __sinf(th) * frcp(th + 1e-9f);
        float4 dm = make_float4(__cosf(th), sc * vx, sc * vy, sc * vz);

        mu = qnorm_fast(hprod(mu, dm));
    }

    // Output 0: barycenter (B, L, 4)
    reinterpret_cast<float4*>(out)[i] = mu;

    // Output 1: eta = angle(det_s)/pi.  det_s imag parts are (a*b - a*b) == 0
    // exactly in fp32; real part = |q|^2 > 0  =>  angle == 0 exactly.
    out[4 * NPTS + i] = 0.0f;

    // Output 2 contribution: |mu - mu/(|mu|+1e-12)|^2  (precise ops, runs once)
    float n = sqrtf(mu.x * mu.x + mu.y * mu.y + mu.z * mu.z + mu.w * mu.w) + 1e-12f;
    float invn = 1.0f / n;
    float dx = mu.x - mu.x * invn;
    float dy = mu.y - mu.y * invn;
    float dz = mu.z - mu.z * invn;
    float dw = mu.w - mu.w * invn;
    float ss = dx * dx + dy * dy + dz * dz + dw * dw;

    // wave(64)-level reduction, one atomic per wave
    #pragma unroll
    for (int off = 32; off > 0; off >>= 1)
        ss += __shfl_down(ss, off, 64);
    if ((threadIdx.x & 63) == 0)
        atomicAdd(acc, ss);
}

__global__ void finish_kernel(const float* __restrict__ acc, float* __restrict__ out)
{
    out[5 * NPTS] = 1.0f / (1.0f + sqrtf(*acc));
}

extern "C" void kernel_launch(void* const* d_in, const int* in_sizes, int n_in,
                              void* d_out, int out_size, void* d_ws, size_t ws_size,
                              hipStream_t stream) {
    const float4* aud = (const float4*)d_in[0];
    const float4* vis = (const float4*)d_in[1];
    const float4* txt = (const float4*)d_in[2];
    const float4* gen = (const float4*)d_in[3];
    float* out = (float*)d_out;
    float* acc = (float*)d_ws;

    // d_ws is poisoned once and never re-poisoned: zero our accumulator each call.
    hipMemsetAsync(acc, 0, sizeof(float), stream);

    karcher_kernel<<<NPTS / 256, 256, 0, stream>>>(aud, vis, txt, gen, out, acc);
    finish_kernel<<<1, 1, 0, stream>>>(acc, out);
}

// Round 3
// 205.771 us; speedup vs baseline: 4.5226x; 4.1648x over previous
//
#include <hip/hip_runtime.h>

// SynesthesiaCentralOrchestrator: per-point Karcher mean of 4 unit quaternions,
// 10 fixed iterations (global convergence flag provably never fires in fp32).
// Quaternion stored as float4: .x=w, .y=x, .z=y, .w=z.
//
// R2: acos/div-free log-map via 4-term poly + v_rsq builtins.
// R3: kill the single-address atomicAdd (65536 waves -> one float serialized
//     ~12ns/op at one L2 slice ~= 800us). Per-block partials to d_ws + one
//     finisher block. No atomics, no memset.

#define NPTS (2048 * 2048)
#define NBLK (NPTS / 256)   // 16384 blocks; ws usage = 64 KB
#define PI_F 3.14159265358979f

__device__ __forceinline__ float frcp(float x) { return __builtin_amdgcn_rcpf(x); }
__device__ __forceinline__ float frsq(float x) { return __builtin_amdgcn_rsqf(x); }
__device__ __forceinline__ float fsqrt(float x) { return __builtin_amdgcn_sqrtf(x); }

__device__ __forceinline__ float4 hprod(const float4 a, const float4 b) {
    // Hamilton product a (x) b
    return make_float4(
        fmaf(a.x, b.x, -fmaf(a.y, b.y, fmaf(a.z, b.z, a.w * b.w))),
        fmaf(a.x, b.y, fmaf(a.y, b.x, fmaf(a.z, b.w, -a.w * b.z))),
        fmaf(a.x, b.z, fmaf(-a.y, b.w, fmaf(a.z, b.x, a.w * b.y))),
        fmaf(a.x, b.w, fmaf(a.y, b.z, fmaf(-a.z, b.y, a.w * b.x))));
}

__device__ __forceinline__ float4 qnorm_fast(const float4 q) {
    float inv = frsq(fmaf(q.x, q.x, fmaf(q.y, q.y, fmaf(q.z, q.z, q.w * q.w))));
    return make_float4(q.x * inv, q.y * inv, q.z * inv, q.w * inv);
}

// Accumulate  s(w) * vec(q)  where q = mi (x) pk,  s(w) = acos(w)/sqrt(1-w^2).
// acos(a) ~= sqrt(1-a) * t(a)  for a in [0,1], |err| <= 6.8e-5 rad.
__device__ __forceinline__ void log_accum(const float4 mi, const float4 pk,
                                          float& vx, float& vy, float& vz) {
    const float4 q = hprod(mi, pk);
    float w = fminf(fmaxf(q.x, -1.0f + 1e-7f), 1.0f - 1e-7f);
    float a = fabsf(w);
    float t = fmaf(a, fmaf(a, fmaf(a, -0.0187293f, 0.0742610f), -0.2121144f), 1.5707288f);
    float r1 = frsq(1.0f + a);
    float r2 = frsq(1.0f - a);          // clamp guarantees 1-a >= 1e-7
    float s = (w >= 0.0f) ? (t * r1) : (r1 * fmaf(PI_F, r2, -t));
    vx = fmaf(s, q.y, vx);
    vy = fmaf(s, q.z, vy);
    vz = fmaf(s, q.w, vz);
}

__global__ __launch_bounds__(256) void karcher_kernel(
    const float4* __restrict__ aud, const float4* __restrict__ vis,
    const float4* __restrict__ txt, const float4* __restrict__ gen,
    float* __restrict__ out, float* __restrict__ ws)
{
    const int i = blockIdx.x * 256 + threadIdx.x;

    float4 p0 = qnorm_fast(aud[i]);
    float4 p1 = qnorm_fast(vis[i]);
    float4 p2 = qnorm_fast(txt[i]);
    float4 p3 = qnorm_fast(gen[i]);

    float4 mu = p0;

    #pragma unroll 1
    for (int it = 0; it < 10; ++it) {
        const float4 mi = make_float4(mu.x, -mu.y, -mu.z, -mu.w);  // mu^-1 (unit)

        float vx = 0.0f, vy = 0.0f, vz = 0.0f;
        log_accum(mi, p0, vx, vy, vz);
        log_accum(mi, p1, vx, vy, vz);
        log_accum(mi, p2, vx, vy, vz);
        log_accum(mi, p3, vx, vy, vz);
        vx *= 0.25f; vy *= 0.25f; vz *= 0.25f;   // weights = 1/4

        // quaternion_exp(mean_v)
        float th = fsqrt(fmaf(vx, vx, fmaf(vy, vy, vz * vz)));
        float sc = __sinf(th) * frcp(th + 1e-9f);
        float4 dm = make_float4(__cosf(th), sc * vx, sc * vy, sc * vz);

        mu = qnorm_fast(hprod(mu, dm));
    }

    // Output 0: barycenter (B, L, 4)
    reinterpret_cast<float4*>(out)[i] = mu;

    // Output 1: eta = angle(det_s)/pi.  det_s imag parts are (a*b - a*b) == 0
    // exactly in fp32; real part = |q|^2 > 0  =>  angle == 0 exactly.
    out[4 * NPTS + i] = 0.0f;

    // Output 2 contribution: |mu - mu/(|mu|+1e-12)|^2  (precise ops, runs once)
    float n = sqrtf(mu.x * mu.x + mu.y * mu.y + mu.z * mu.z + mu.w * mu.w) + 1e-12f;
    float invn = 1.0f / n;
    float dx = mu.x - mu.x * invn;
    float dy = mu.y - mu.y * invn;
    float dz = mu.z - mu.z * invn;
    float dw = mu.w - mu.w * invn;
    float ss = dx * dx + dy * dy + dz * dz + dw * dw;

    // wave(64) shfl reduce -> LDS across the 4 waves -> one plain store/block
    #pragma unroll
    for (int off = 32; off > 0; off >>= 1)
        ss += __shfl_down(ss, off, 64);
    __shared__ float part[4];
    if ((threadIdx.x & 63) == 0) part[threadIdx.x >> 6] = ss;
    __syncthreads();
    if (threadIdx.x == 0)
        ws[blockIdx.x] = part[0] + part[1] + part[2] + part[3];
}

__global__ __launch_bounds__(256) void finish_kernel(
    const float* __restrict__ ws, float* __restrict__ out)
{
    float s = 0.0f;
    #pragma unroll 4
    for (int k = threadIdx.x; k < NBLK; k += 256)
        s += ws[k];
    #pragma unroll
    for (int off = 32; off > 0; off >>= 1)
        s += __shfl_down(s, off, 64);
    __shared__ float part[4];
    if ((threadIdx.x & 63) == 0) part[threadIdx.x >> 6] = s;
    __syncthreads();
    if (threadIdx.x == 0)
        out[5 * NPTS] = 1.0f / (1.0f + sqrtf(part[0] + part[1] + part[2] + part[3]));
}

extern "C" void kernel_launch(void* const* d_in, const int* in_sizes, int n_in,
                              void* d_out, int out_size, void* d_ws, size_t ws_size,
                              hipStream_t stream) {
    const float4* aud = (const float4*)d_in[0];
    const float4* vis = (const float4*)d_in[1];
    const float4* txt = (const float4*)d_in[2];
    const float4* gen = (const float4*)d_in[3];
    float* out = (float*)d_out;
    float* ws = (float*)d_ws;   // NBLK floats, fully overwritten every call

    karcher_kernel<<<NBLK, 256, 0, stream>>>(aud, vis, txt, gen, out, ws);
    finish_kernel<<<1, 256, 0, stream>>>(ws, out);
}

// Round 4
// 178.106 us; speedup vs baseline: 5.2251x; 1.1553x over previous
//
#include <hip/hip_runtime.h>

// SynesthesiaCentralOrchestrator: per-point Karcher mean of 4 unit quaternions,
// 10 fixed iterations (global convergence flag provably never fires in fp32).
// Quaternion stored as float4: .x=w, .y=x, .z=y, .w=z.
//
// R2: acos/div-free log-map via 4-term poly + v_rsq builtins.
// R3: per-block partials instead of single-address atomicAdd (was ~800us drain).
// R4: VALU-issue-bound (99% busy) -> cut instructions algebraically:
//     (a) log-map needs only w_k = <mu, p_k>; weighted tangent sum via
//         sum s_k vec(mu^-1 (x) p_k) = m0*S - sigma*m - m x S   (linear in p_k)
//     (b) 1/4 weights folded into acos-poly coefficients and pi
//     (c) no per-iteration renormalize of mu (|mu| drifts <= ~1e-6 over 10
//         iters; exp(v) is unit to 1 ulp); normalize once at the end.

#define NPTS (2048 * 2048)
#define NBLK (NPTS / 256)   // 16384 blocks; ws usage = 64 KB

__device__ __forceinline__ float frcp(float x) { return __builtin_amdgcn_rcpf(x); }
__device__ __forceinline__ float frsq(float x) { return __builtin_amdgcn_rsqf(x); }
__device__ __forceinline__ float fsqrt(float x) { return __builtin_amdgcn_sqrtf(x); }

__device__ __forceinline__ float4 qnorm_fast(const float4 q) {
    float inv = frsq(fmaf(q.x, q.x, fmaf(q.y, q.y, fmaf(q.z, q.z, q.w * q.w))));
    return make_float4(q.x * inv, q.y * inv, q.z * inv, q.w * inv);
}

// s'(w) = 0.25 * acos(w)/sqrt(1-w^2)  via  acos(a) ~= sqrt(1-a)*t(a), a=|w|
// (A&S 4.4.45, |err| <= 6.8e-5 rad). Coefficients pre-scaled by 0.25.
__device__ __forceinline__ float log_scale(float w) {
    float wc = fminf(fmaxf(w, -1.0f + 1e-7f), 1.0f - 1e-7f);
    float a = fabsf(wc);
    float t = fmaf(a, fmaf(a, fmaf(a, -0.004682325f, 0.018565250f), -0.053028600f),
                   0.392682200f);                       // 0.25 * t(a)
    float r1 = frsq(1.0f + a);
    float r2 = frsq(1.0f - a);                          // clamp keeps 1-a >= 1e-7
    float u = fmaf(0.785398163f, r2, -t);               // (pi/4)*r2 - t
    return r1 * ((w >= 0.0f) ? t : u);
}

__global__ __launch_bounds__(256) void karcher_kernel(
    const float4* __restrict__ aud, const float4* __restrict__ vis,
    const float4* __restrict__ txt, const float4* __restrict__ gen,
    float* __restrict__ out, float* __restrict__ ws)
{
    const int i = blockIdx.x * 256 + threadIdx.x;

    float4 p0 = qnorm_fast(aud[i]);
    float4 p1 = qnorm_fast(vis[i]);
    float4 p2 = qnorm_fast(txt[i]);
    float4 p3 = qnorm_fast(gen[i]);

    float4 mu = p0;

    #pragma unroll 1
    for (int it = 0; it < 10; ++it) {
        // w_k = Re(mu^-1 (x) p_k) = <mu, p_k>   (mu unit to ~1e-6)
        float w0 = fmaf(mu.x, p0.x, fmaf(mu.y, p0.y, fmaf(mu.z, p0.z, mu.w * p0.w)));
        float w1 = fmaf(mu.x, p1.x, fmaf(mu.y, p1.y, fmaf(mu.z, p1.z, mu.w * p1.w)));
        float w2 = fmaf(mu.x, p2.x, fmaf(mu.y, p2.y, fmaf(mu.z, p2.z, mu.w * p2.w)));
        float w3 = fmaf(mu.x, p3.x, fmaf(mu.y, p3.y, fmaf(mu.z, p3.z, mu.w * p3.w)));

        float s0 = log_scale(w0), s1 = log_scale(w1), s2 = log_scale(w2), s3 = log_scale(w3);

        // S = sum s_k * vec(p_k);  sigma = sum s_k * w-comp(p_k)
        float Sx = fmaf(s0, p0.y, fmaf(s1, p1.y, fmaf(s2, p2.y, s3 * p3.y)));
        float Sy = fmaf(s0, p0.z, fmaf(s1, p1.z, fmaf(s2, p2.z, s3 * p3.z)));
        float Sz = fmaf(s0, p0.w, fmaf(s1, p1.w, fmaf(s2, p2.w, s3 * p3.w)));
        float sg = fmaf(s0, p0.x, fmaf(s1, p1.x, fmaf(s2, p2.x, s3 * p3.x)));

        // mean_v = m0*S - sigma*m - m x S   (weights already folded into s_k)
        float cx = fmaf(mu.z, Sz, -mu.w * Sy);
        float cy = fmaf(mu.w, Sx, -mu.y * Sz);
        float cz = fmaf(mu.y, Sy, -mu.z * Sx);
        float vx = fmaf(mu.x, Sx, -fmaf(sg, mu.y, cx));
        float vy = fmaf(mu.x, Sy, -fmaf(sg, mu.z, cy));
        float vz = fmaf(mu.x, Sz, -fmaf(sg, mu.w, cz));

        // delta_mu = exp(mean_v)
        float th = fsqrt(fmaf(vx, vx, fmaf(vy, vy, vz * vz)));
        float sc = __sinf(th) * frcp(th + 1e-9f);
        float dw = __cosf(th);
        float dx = sc * vx, dy = sc * vy, dz = sc * vz;

        // mu = mu (x) dm   (no renormalize; drift ~1ulp/iter)
        float4 nmu;
        nmu.x = fmaf(mu.x, dw, -fmaf(mu.y, dx, fmaf(mu.z, dy, mu.w * dz)));
        nmu.y = fmaf(mu.x, dx, fmaf(mu.y, dw, fmaf(mu.z, dz, -mu.w * dy)));
        nmu.z = fmaf(mu.x, dy, fmaf(-mu.y, dz, fmaf(mu.z, dw, mu.w * dx)));
        nmu.w = fmaf(mu.x, dz, fmaf(mu.y, dy, fmaf(-mu.z, dx, mu.w * dw)));
        mu = nmu;
    }

    mu = qnorm_fast(mu);   // reference's final barycenter is normalized

    // Output 0: barycenter (B, L, 4)
    reinterpret_cast<float4*>(out)[i] = mu;

    // Output 1: eta = angle(det_s)/pi. det_s imag parts are (a*b - a*b) == 0
    // exactly in fp32; real part = |q|^2 > 0  =>  angle == 0 exactly.
    out[4 * NPTS + i] = 0.0f;

    // Output 2 contribution: |mu - mu/(|mu|+1e-12)|^2  (precise ops, runs once)
    float n = sqrtf(mu.x * mu.x + mu.y * mu.y + mu.z * mu.z + mu.w * mu.w) + 1e-12f;
    float invn = 1.0f / n;
    float ex = mu.x - mu.x * invn;
    float ey = mu.y - mu.y * invn;
    float ez = mu.z - mu.z * invn;
    float ew = mu.w - mu.w * invn;
    float ss = ex * ex + ey * ey + ez * ez + ew * ew;

    // wave(64) shfl reduce -> LDS across the 4 waves -> one plain store/block
    #pragma unroll
    for (int off = 32; off > 0; off >>= 1)
        ss += __shfl_down(ss, off, 64);
    __shared__ float part[4];
    if ((threadIdx.x & 63) == 0) part[threadIdx.x >> 6] = ss;
    __syncthreads();
    if (threadIdx.x == 0)
        ws[blockIdx.x] = part[0] + part[1] + part[2] + part[3];
}

__global__ __launch_bounds__(256) void finish_kernel(
    const float* __restrict__ ws, float* __restrict__ out)
{
    float s = 0.0f;
    #pragma unroll 4
    for (int k = threadIdx.x; k < NBLK; k += 256)
        s += ws[k];
    #pragma unroll
    for (int off = 32; off > 0; off >>= 1)
        s += __shfl_down(s, off, 64);
    __shared__ float part[4];
    if ((threadIdx.x & 63) == 0) part[threadIdx.x >> 6] = s;
    __syncthreads();
    if (threadIdx.x == 0)
        out[5 * NPTS] = 1.0f / (1.0f + sqrtf(part[0] + part[1] + part[2] + part[3]));
}

extern "C" void kernel_launch(void* const* d_in, const int* in_sizes, int n_in,
                              void* d_out, int out_size, void* d_ws, size_t ws_size,
                              hipStream_t stream) {
    const float4* aud = (const float4*)d_in[0];
    const float4* vis = (const float4*)d_in[1];
    const float4* txt = (const float4*)d_in[2];
    const float4* gen = (const float4*)d_in[3];
    float* out = (float*)d_out;
    float* ws = (float*)d_ws;   // NBLK floats, fully overwritten every call

    karcher_kernel<<<NBLK, 256, 0, stream>>>(aud, vis, txt, gen, out, ws);
    finish_kernel<<<1, 256, 0, stream>>>(ws, out);
}